// Round 7
// baseline (112.319 us; speedup 1.0000x reference)
//
#include <hip/hip_runtime.h>
#include <hip/hip_bf16.h>

#define BB 8
#define NN 16384
#define D1 256
#define D2 64
#define DT 320
#define EPSF 1e-12f
#define NCG 32          // K chunks (both paths)
#define KCH 512         // rows per chunk
#define QSZ (160*320)   // mode-1 partial slice elems
#define Q2SZ (160*160)  // mode-2 quarter slice elems

typedef __attribute__((ext_vector_type(8))) short bf16x8;
typedef __attribute__((ext_vector_type(8))) unsigned short u16x8;
typedef __attribute__((ext_vector_type(4))) unsigned short u16x4;
typedef __attribute__((ext_vector_type(4))) float f32x4;
typedef __attribute__((ext_vector_type(4))) unsigned int u32x4;

__device__ __forceinline__ unsigned int packbf2(float a, float b) {
    unsigned short lo = __builtin_bit_cast(unsigned short, __float2bfloat16(a));
    unsigned short hi = __builtin_bit_cast(unsigned short, __float2bfloat16(b));
    return (unsigned int)lo | ((unsigned int)hi << 16);
}
__device__ __forceinline__ unsigned short f2bfu(float f) {
    return __builtin_bit_cast(unsigned short, __float2bfloat16(f));
}
__device__ __forceinline__ float bf2f(unsigned short u) {
    unsigned int x = (unsigned int)u << 16;
    return __builtin_bit_cast(float, x);
}

__device__ __forceinline__ int sig(int c) { return (c ^ (c >> 2)) & 7; }   // mode-1 8-unit
__device__ __forceinline__ int sig4(int c) { return (c ^ (c >> 2)) & 3; }  // mode-2 4-unit

// async 16B/lane global->LDS DMA; lds base wave-uniform, global addr per-lane
__device__ __forceinline__ void gload16(const unsigned short* g, unsigned short* l) {
    __builtin_amdgcn_global_load_lds(
        (const __attribute__((address_space(1))) unsigned int*)(g),
        (__attribute__((address_space(3))) unsigned int*)(l), 16, 0, 0);
}

// ---------------- kernel 1: s[b,c] = sum_n Y[b,n,c] ----------------
__global__ void colsum_kernel(const float* __restrict__ Y, float* __restrict__ s) {
    const int b = blockIdx.y;
    const int chunk = blockIdx.x;
    const int t = threadIdx.x;
    const int c = t & 63;
    const int r = t >> 6;
    const float* Yb = Y + (size_t)b * NN * D2;
    float acc = 0.f;
    const int nbase = chunk * 512;
    for (int k = 0; k < 128; ++k) {
        int n = nbase + k * 4 + r;
        acc += Yb[(size_t)n * D2 + c];
    }
    __shared__ float red[256];
    red[t] = acc;
    __syncthreads();
    if (r == 0) {
        float v = red[c] + red[64 + c] + red[128 + c] + red[192 + c];
        atomicAdd(&s[b * D2 + c], v);
    }
}

// ---------------- kernel 2: rsd[b,n] = (Y[b,n,:].s[b,:] + eps)^(-1/4) ----------------
__global__ void rsd_kernel(const float* __restrict__ Y, const float* __restrict__ s,
                           float* __restrict__ rsd) {
    const int blk = blockIdx.x;
    const int b = blk >> 8;
    const int nb = (blk & 255) * 64;
    const int t = threadIdx.x;
    const int q = t & 3;
    const int nl = t >> 2;
    __shared__ float ss[D2];
    if (t < D2) ss[t] = s[b * D2 + t];
    __syncthreads();
    const int n = nb + nl;
    const float* yrow = Y + (size_t)b * NN * D2 + (size_t)n * D2 + q * 16;
    float dot = 0.f;
#pragma unroll
    for (int i = 0; i < 4; ++i) {
        float4 f = *reinterpret_cast<const float4*>(yrow + i * 4);
        const float* sp = ss + q * 16 + i * 4;
        dot += f.x * sp[0] + f.y * sp[1] + f.z * sp[2] + f.w * sp[3];
    }
    dot += __shfl_xor(dot, 1);
    dot += __shfl_xor(dot, 2);
    if (q == 0) {
        rsd[(size_t)b * NN + n] = rsqrtf(sqrtf(dot + EPSF));
    }
}

// ---------------- kernel 2.5 (mode 2): Xt[b][c][n] = bf16(rsd[n] * X[n][c]) -------
// grid (64 nblk, 5 cseg, 8 b), 256 threads; tile 256 n x 64 c via LDS transpose
__global__ void xt_kernel(const float* __restrict__ V, const float* __restrict__ Y,
                          const float* __restrict__ rsd, unsigned short* __restrict__ Xt) {
    const int nblk = blockIdx.x;
    const int cseg = blockIdx.y;
    const int b = blockIdx.z;
    const int t = threadIdx.x;
    const int n0 = nblk * 256;
    const bool isY = (cseg == 4);
    const float* src = isY ? (Y + (size_t)b * NN * D2) : (V + (size_t)b * NN * D1);
    const int ld = isY ? D2 : D1;
    const int scol0 = isY ? 0 : cseg * 64;
    const int gcol0 = isY ? D1 : cseg * 64;
    const float* rb = rsd + (size_t)b * NN;

    __shared__ __attribute__((aligned(16))) unsigned short tile[64][264]; // pad->16B rows

    const int rl = t >> 4;          // 0..15
    const int cq = (t & 15) * 4;    // 0..60
#pragma unroll 4
    for (int r = 0; r < 16; ++r) {
        const int nl = r * 16 + rl;
        const int n = n0 + nl;
        float4 f = *reinterpret_cast<const float4*>(src + (size_t)n * ld + scol0 + cq);
        const float sc = rb[n];
        tile[cq + 0][nl] = f2bfu(f.x * sc);
        tile[cq + 1][nl] = f2bfu(f.y * sc);
        tile[cq + 2][nl] = f2bfu(f.z * sc);
        tile[cq + 3][nl] = f2bfu(f.w * sc);
    }
    __syncthreads();
    const int cl = t >> 5;          // 0..7
    const int seg = t & 31;         // 0..31 (8 n each)
#pragma unroll
    for (int p = 0; p < 8; ++p) {
        const int c = p * 8 + cl;
        u32x4 v = *reinterpret_cast<const u32x4*>(&tile[c][seg * 8]);
        *reinterpret_cast<u32x4*>(Xt + ((size_t)b * DT + gcol0 + c) * NN + n0 + seg * 8) = v;
    }
}

// ---------------- kernel 3 (mode 2): quarter Gram from Xt via global_load_lds ------
// grid (32 cg, 3 qq, 8 b) = 768 blocks (3/CU); 256 thr (4 waves 2x2 of 80x80)
// qq: 0->(0,0) 1->(0,1) 2->(1,1); q10 recovered by symmetry in the reducer.
__global__ void __launch_bounds__(256, 3)
gram2_kernel(const unsigned short* __restrict__ Xt, unsigned short* __restrict__ Gp2) {
    const int cg = blockIdx.x;
    const int qq = blockIdx.y;
    const int b = blockIdx.z;
    const int qi = (qq == 2) ? 1 : 0;
    const int qj = (qq == 0) ? 0 : 1;
    const int t = threadIdx.x;
    const int lane = t & 63;
    const int w = t >> 6;
    const int wrow = w >> 1, wcol = w & 1;
    const int l15 = lane & 15, l4 = lane >> 4;

    const unsigned short* Xb = Xt + (size_t)b * DT * NN;

    // double-buffered [320 c][4 units x 8 n] bf16 = 2 x 20 KB
    __shared__ __attribute__((aligned(16))) unsigned short xb[2][DT * 32];

    f32x4 acc[5][5];
#pragma unroll
    for (int i = 0; i < 5; ++i)
#pragma unroll
        for (int j = 0; j < 5; ++j)
            acc[i][j] = (f32x4){0.f, 0.f, 0.f, 0.f};

    const int cR = lane >> 2;   // 0..15: c row within 16-c instr group
    const int uL = lane & 3;    // LDS unit this lane fills
    const int n0base = cg * KCH;

    // stage one 320x32 tile into buf: 5 DMA instrs/wave (wave w covers c = 80w..80w+79)
    // LDS linear dest (base + lane*16B); swizzle applied on the GLOBAL address side.
#define STAGE2(buf, n0)                                                        \
    {                                                                          \
        _Pragma("unroll")                                                      \
        for (int i2 = 0; i2 < 5; ++i2) {                                       \
            const int c0 = w * 80 + i2 * 16;                                   \
            const int c = c0 + cR;                                             \
            const int n8 = uL ^ sig4(c);                                       \
            gload16(Xb + (size_t)c * NN + (n0) + n8 * 8, &xb[buf][c0 * 32]);   \
        }                                                                      \
    }

    STAGE2(0, n0base);
    __syncthreads();            // implicit vmcnt(0) drain -> tile 0 resident

    int cur = 0;
    for (int tt = 0; tt < 16; ++tt) {
        if (tt < 15) STAGE2(cur ^ 1, n0base + (tt + 1) * 32);  // async, in flight
        const unsigned short* x = xb[cur];
        bf16x8 af[5], bfr[5];
#pragma unroll
        for (int i = 0; i < 5; ++i) {
            const int ca = qi * 160 + wrow * 80 + i * 16 + l15;
            af[i] = *reinterpret_cast<const bf16x8*>(
                &x[ca * 32 + ((l4 ^ sig4(ca)) & 3) * 8]);
            const int cb = qj * 160 + wcol * 80 + i * 16 + l15;
            bfr[i] = *reinterpret_cast<const bf16x8*>(
                &x[cb * 32 + ((l4 ^ sig4(cb)) & 3) * 8]);
        }
#pragma unroll
        for (int i = 0; i < 5; ++i)
#pragma unroll
            for (int j = 0; j < 5; ++j)
                acc[i][j] = __builtin_amdgcn_mfma_f32_16x16x32_bf16(
                    af[i], bfr[j], acc[i][j], 0, 0, 0);
        __syncthreads();        // reads done + next tile's DMA drained
        cur ^= 1;
    }

    // epilogue: bf16 quarter partial [160][160]
    unsigned short* Gp = Gp2 + (size_t)((b * 3 + qq) * NCG + cg) * Q2SZ;
#pragma unroll
    for (int i = 0; i < 5; ++i) {
        const int gi_base = wrow * 80 + i * 16 + l4 * 4;
#pragma unroll
        for (int j = 0; j < 5; ++j) {
            const int gj = wcol * 80 + j * 16 + l15;
#pragma unroll
            for (int rg = 0; rg < 4; ++rg)
                Gp[(size_t)(gi_base + rg) * 160 + gj] = f2bfu(acc[i][j][rg]);
        }
    }
#undef STAGE2
}

// ---------------- kernel 4 (mode 2): reduce quarters, weighted square sum ----------
// grid (25, 24): y = b*3+qq; x: 1024-elem slices of 160x160 (4/thread)
__global__ void loss2_kernel(const unsigned short* __restrict__ Gp2,
                             float* __restrict__ out) {
    const int byq = blockIdx.y;
    const int qq = byq % 3;
    const int qi = (qq == 2) ? 1 : 0;
    const int qj = (qq == 0) ? 0 : 1;
    const int t = threadIdx.x;
    const int e0 = (blockIdx.x * 256 + t) * 4;    // < 25600
    float g0 = 0.f, g1 = 0.f, g2 = 0.f, g3 = 0.f;
    const unsigned short* base = Gp2 + (size_t)byq * NCG * Q2SZ + e0;
#pragma unroll 4
    for (int cg = 0; cg < NCG; ++cg) {
        u16x4 p = *reinterpret_cast<const u16x4*>(base + (size_t)cg * Q2SZ);
        g0 += bf2f(p[0]); g1 += bf2f(p[1]); g2 += bf2f(p[2]); g3 += bf2f(p[3]);
    }
    const int ii = e0 / 160;
    const int jj = e0 - ii * 160;                 // multiple of 4; 256-boundary 4-aligned
    const int ig = qi * 160 + ii;
    const int jg = qj * 160 + jj;
    const float wgt = ((ig < D1) == (jg < D1)) ? 1.f : -1.f;
    const float mult = (qq == 1) ? 2.f : 1.f;     // symmetric off-diagonal block
    float sum = wgt * mult * (g0 * g0 + g1 * g1 + g2 * g2 + g3 * g3);
#pragma unroll
    for (int off = 1; off < 64; off <<= 1) sum += __shfl_xor(sum, off);
    __shared__ float red[4];
    if ((t & 63) == 0) red[t >> 6] = sum;
    __syncthreads();
    if (t == 0) atomicAdd(out, (red[0] + red[1] + red[2] + red[3]) * 0.125f);
}

// ================= mode-1 fallback: R6 proven path =================
__device__ __forceinline__ void issue_loads(const float* __restrict__ Vb,
                                            const float* __restrict__ Yb,
                                            const float* __restrict__ rb,
                                            int n0w, int lane,
                                            float4* vf, float4* yf, float* rr) {
#pragma unroll
    for (int j = 0; j < 8; ++j)
        vf[j] = *reinterpret_cast<const float4*>(Vb + (size_t)(n0w + j) * D1 + 4 * lane);
    const int j2 = lane >> 4, k15 = lane & 15;
    yf[0] = *reinterpret_cast<const float4*>(Yb + (size_t)(n0w + 2 * j2) * D2 + 4 * k15);
    yf[1] = *reinterpret_cast<const float4*>(Yb + (size_t)(n0w + 2 * j2 + 1) * D2 + 4 * k15);
#pragma unroll
    for (int j = 0; j < 8; ++j) rr[j] = rb[n0w + j];
}

__device__ __forceinline__ void write_tile(unsigned short* __restrict__ x,
                                           int lane, int w,
                                           const float4* vf, const float4* yf,
                                           const float* rr) {
    const float* vfp = reinterpret_cast<const float*>(vf);
    const float* yfp = reinterpret_cast<const float*>(yf);
#pragma unroll
    for (int cidx = 0; cidx < 4; ++cidx) {
        const int c = 4 * lane + cidx;
        const int u = (w ^ sig(c)) & 7;
        u32x4 p;
        p[0] = packbf2(vfp[0 * 4 + cidx] * rr[0], vfp[1 * 4 + cidx] * rr[1]);
        p[1] = packbf2(vfp[2 * 4 + cidx] * rr[2], vfp[3 * 4 + cidx] * rr[3]);
        p[2] = packbf2(vfp[4 * 4 + cidx] * rr[4], vfp[5 * 4 + cidx] * rr[5]);
        p[3] = packbf2(vfp[6 * 4 + cidx] * rr[6], vfp[7 * 4 + cidx] * rr[7]);
        *reinterpret_cast<u32x4*>(&x[c * 64 + u * 8]) = p;
    }
    const int j2 = lane >> 4, k15 = lane & 15;
    const float r0 = rr[2 * j2], r1 = rr[2 * j2 + 1];
#pragma unroll
    for (int cidx = 0; cidx < 4; ++cidx) {
        const int c = D1 + 4 * k15 + cidx;
        const int u = (w ^ sig(c)) & 7;
        unsigned int p = packbf2(yfp[0 * 4 + cidx] * r0, yfp[1 * 4 + cidx] * r1);
        *reinterpret_cast<unsigned int*>(&x[c * 64 + u * 8 + j2 * 2]) = p;
    }
}

__global__ void __launch_bounds__(512, 2)
gram_kernel(const float* __restrict__ V, const float* __restrict__ Y,
            const float* __restrict__ rsd, unsigned short* __restrict__ Gpart,
            float* __restrict__ Gfull, int priv) {
    const int cg = blockIdx.x;
    const int band = blockIdx.y;
    const int b = blockIdx.z;
    const int t = threadIdx.x;
    const int lane = t & 63;
    const int w = t >> 6;
    const int wrow = w >> 2;
    const int wcol = w & 3;
    const int l15 = lane & 15;
    const int l4 = lane >> 4;

    const float* Vb = V + (size_t)b * NN * D1;
    const float* Yb = Y + (size_t)b * NN * D2;
    const float* rb = rsd + (size_t)b * NN;

    __shared__ __attribute__((aligned(16))) unsigned short xt[DT * 64];

    f32x4 acc[5][5];
#pragma unroll
    for (int i = 0; i < 5; ++i)
#pragma unroll
        for (int j = 0; j < 5; ++j)
            acc[i][j] = (f32x4){0.f, 0.f, 0.f, 0.f};

    float4 vf[8];
    float4 yf[2];
    float rr[8];

    const int n0base = cg * KCH;

    issue_loads(Vb, Yb, rb, n0base + 8 * w, lane, vf, yf, rr);
    write_tile(xt, lane, w, vf, yf, rr);

    for (int tt = 0; tt < 8; ++tt) {
        __syncthreads();
        if (tt < 7)
            issue_loads(Vb, Yb, rb, n0base + (tt + 1) * 64 + 8 * w, lane, vf, yf, rr);
#pragma unroll
        for (int ks = 0; ks < 2; ++ks) {
            const int n8r = 2 * l4 + ks;
            bf16x8 af[5], bfr[5];
#pragma unroll
            for (int i = 0; i < 5; ++i) {
                const int ca = band * 160 + wrow * 80 + i * 16 + l15;
                af[i] = *reinterpret_cast<const bf16x8*>(
                    &xt[ca * 64 + ((n8r ^ sig(ca)) & 7) * 8]);
                const int cb = wcol * 80 + i * 16 + l15;
                bfr[i] = *reinterpret_cast<const bf16x8*>(
                    &xt[cb * 64 + ((n8r ^ sig(cb)) & 7) * 8]);
            }
#pragma unroll
            for (int i = 0; i < 5; ++i)
#pragma unroll
                for (int j = 0; j < 5; ++j)
                    acc[i][j] = __builtin_amdgcn_mfma_f32_16x16x32_bf16(
                        af[i], bfr[j], acc[i][j], 0, 0, 0);
        }
        __syncthreads();
        if (tt < 7)
            write_tile(xt, lane, w, vf, yf, rr);
    }

    if (priv) {
        unsigned short* Gp = Gpart + (size_t)((b * 2 + band) * NCG + cg) * QSZ;
#pragma unroll
        for (int i = 0; i < 5; ++i) {
            const int gi_base = wrow * 80 + i * 16 + l4 * 4;
#pragma unroll
            for (int j = 0; j < 5; ++j) {
                const int gj = wcol * 80 + j * 16 + l15;
#pragma unroll
                for (int rg = 0; rg < 4; ++rg)
                    Gp[(size_t)(gi_base + rg) * DT + gj] = f2bfu(acc[i][j][rg]);
            }
        }
    } else {
        float* Gb = Gfull + (size_t)b * DT * DT;
#pragma unroll
        for (int i = 0; i < 5; ++i) {
            const int gi_base = band * 160 + wrow * 80 + i * 16 + l4 * 4;
#pragma unroll
            for (int j = 0; j < 5; ++j) {
                const int gj = wcol * 80 + j * 16 + l15;
#pragma unroll
                for (int rg = 0; rg < 4; ++rg)
                    atomicAdd(&Gb[(size_t)(gi_base + rg) * DT + gj], acc[i][j][rg]);
            }
        }
    }
}

__global__ void loss_priv_kernel(const unsigned short* __restrict__ Gpart,
                                 float* __restrict__ out) {
    const int by = blockIdx.y;
    const int band = by & 1;
    const int t = threadIdx.x;
    const int e0 = (blockIdx.x * 256 + t) * 8;
    float g[8];
#pragma unroll
    for (int k = 0; k < 8; ++k) g[k] = 0.f;
    const unsigned short* base = Gpart + (size_t)by * NCG * QSZ + e0;
#pragma unroll 4
    for (int cg = 0; cg < NCG; ++cg) {
        u16x8 p = *reinterpret_cast<const u16x8*>(base + (size_t)cg * QSZ);
#pragma unroll
        for (int k = 0; k < 8; ++k) g[k] += bf2f(p[k]);
    }
    const int ii = e0 / DT;
    const int jj = e0 - ii * DT;
    const int ig = band * 160 + ii;
    const float wgt = ((ig < D1) == (jj < D1)) ? 1.f : -1.f;
    float sum = 0.f;
#pragma unroll
    for (int k = 0; k < 8; ++k) sum += g[k] * g[k];
    sum *= wgt;
#pragma unroll
    for (int off = 1; off < 64; off <<= 1) sum += __shfl_xor(sum, off);
    __shared__ float red[4];
    if ((t & 63) == 0) red[t >> 6] = sum;
    __syncthreads();
    if (t == 0) atomicAdd(out, (red[0] + red[1] + red[2] + red[3]) * 0.125f);
}

__global__ void loss_kernel(const float* __restrict__ G, float* __restrict__ out) {
    const int b = blockIdx.x >> 3;
    const int slice = blockIdx.x & 7;
    const int t = threadIdx.x;
    const float* Gb = G + (size_t)b * DT * DT;
    float sum = 0.f;
    for (int k = 0; k < 50; ++k) {
        const int e = slice * 12800 + k * 256 + t;
        const int i = e / DT;
        const int j = e - i * DT;
        const float gv = Gb[e];
        const float w = ((i < D1) == (j < D1)) ? 1.f : -1.f;
        sum += w * gv * gv;
    }
#pragma unroll
    for (int off = 1; off < 64; off <<= 1) sum += __shfl_xor(sum, off);
    __shared__ float red[4];
    if ((t & 63) == 0) red[t >> 6] = sum;
    __syncthreads();
    if (t == 0) atomicAdd(out, (red[0] + red[1] + red[2] + red[3]) * 0.125f);
}

extern "C" void kernel_launch(void* const* d_in, const int* in_sizes, int n_in,
                              void* d_out, int out_size, void* d_ws, size_t ws_size,
                              hipStream_t stream) {
    const float* V = (const float*)d_in[0];
    const float* Y = (const float*)d_in[1];
    float* out = (float*)d_out;

    char* ws = (char*)d_ws;
    float* s   = (float*)ws;                          // 2048 B
    float* rsd = (float*)(ws + 2048);                 // 524288 B

    const size_t XT_OFF = 2048 + 524288;              // 526336 (16B aligned)
    const size_t XT_BYTES = (size_t)BB * DT * NN * 2; // 83,886,080
    const size_t GP2_OFF = XT_OFF + XT_BYTES;
    const size_t GP2_BYTES = (size_t)BB * 3 * NCG * Q2SZ * 2;  // 39,321,600
    const size_t need2 = GP2_OFF + GP2_BYTES;                  // ~124 MB
    const size_t need1 = XT_OFF + (size_t)BB * 2 * NCG * QSZ * 2;

    hipMemsetAsync(s, 0, 2048, stream);
    hipMemsetAsync(d_out, 0, sizeof(float), stream);

    colsum_kernel<<<dim3(32, BB), 256, 0, stream>>>(Y, s);
    rsd_kernel<<<2048, 256, 0, stream>>>(Y, s, rsd);

    if (ws_size >= need2) {
        unsigned short* Xt  = (unsigned short*)(ws + XT_OFF);
        unsigned short* Gp2 = (unsigned short*)(ws + GP2_OFF);
        xt_kernel<<<dim3(64, 5, BB), 256, 0, stream>>>(V, Y, rsd, Xt);
        gram2_kernel<<<dim3(NCG, 3, BB), 256, 0, stream>>>(Xt, Gp2);
        loss2_kernel<<<dim3(25, 24), 256, 0, stream>>>(Gp2, out);
    } else if (ws_size >= need1) {
        unsigned short* Gpart = (unsigned short*)(ws + XT_OFF);
        gram_kernel<<<dim3(NCG, 2, BB), 512, 0, stream>>>(V, Y, rsd, Gpart, nullptr, 1);
        loss_priv_kernel<<<dim3(25, 16), 256, 0, stream>>>(Gpart, out);
    } else {
        float* Gfull = (float*)(ws + XT_OFF);
        hipMemsetAsync(Gfull, 0, (size_t)BB * DT * DT * 4, stream);
        gram_kernel<<<dim3(NCG, 2, BB), 512, 0, stream>>>(V, Y, rsd, nullptr, Gfull, 0);
        loss_kernel<<<64, 256, 0, stream>>>(Gfull, out);
    }
}